// Round 9
// baseline (265.884 us; speedup 1.0000x reference)
//
#include <hip/hip_runtime.h>
#include <hip/hip_cooperative_groups.h>
#include <math.h>

namespace cg = cooperative_groups;

#define BATCH 2
#define SEQ   4096
#define DIN   256
#define NH    8
#define DH    32            // head dim (dk = dv = 32)
#define BH    (BATCH*NH)    // 16
#define TILES (SEQ/64)      // 64 key-tiles per attn block (no split)

typedef short bf16x8 __attribute__((ext_vector_type(8)));
typedef float f32x4  __attribute__((ext_vector_type(4)));

// raw v_exp_f32 (base-2). Scores bounded -> no denorm fixup needed.
#if defined(__has_builtin)
#if __has_builtin(__builtin_amdgcn_exp2f)
#define EXP2(x) __builtin_amdgcn_exp2f(x)
#else
#define EXP2_ASM 1
#endif
#else
#define EXP2_ASM 1
#endif
#ifdef EXP2_ASM
__device__ __forceinline__ float exp2_raw(float x) {
    float r;
    asm("v_exp_f32 %0, %1\n\ts_nop 1" : "=v"(r) : "v"(x));
    return r;
}
#define EXP2(x) exp2_raw(x)
#endif

#define SC2 0.25508218f     // log2(e)/sqrt(32) — folded into Q at projection

__device__ __forceinline__ unsigned short f2bf(float f) {
    unsigned int u = __builtin_bit_cast(unsigned int, f);
    u += 0x7fffu + ((u >> 16) & 1u);
    return (unsigned short)(u >> 16);
}

// pack 2 rounded bf16 (round-half-up), one v_perm + 2 adds
__device__ __forceinline__ unsigned int pack_bf2(float f0, float f1) {
    unsigned int u0 = __builtin_bit_cast(unsigned int, f0) + 0x8000u;
    unsigned int u1 = __builtin_bit_cast(unsigned int, f1) + 0x8000u;
    return __builtin_amdgcn_perm(u1, u0, 0x07060302u);
}

// pack 2 TRUNCATED bf16, single v_perm (hot attn loop). Truncation bias
// cancels exactly in softmax: l is computed from the same truncated P.
__device__ __forceinline__ unsigned int pack_bf2_t(float f0, float f1) {
    return __builtin_amdgcn_perm(__builtin_bit_cast(unsigned int, f1),
                                 __builtin_bit_cast(unsigned int, f0),
                                 0x07060302u);
}

#if defined(__has_builtin)
#if __has_builtin(__builtin_amdgcn_global_load_lds)
#define HAS_ASYNC_LDS 1
#endif
#endif

// async global->LDS, 16B/lane: wave-uniform LDS base, HW scatters lane i to
// base + i*16 (verified R5-R8).
__device__ __forceinline__ void stage16(const unsigned short* g,
                                        unsigned short* lds_base, int lane) {
#ifdef HAS_ASYNC_LDS
    __builtin_amdgcn_global_load_lds(
        (const __attribute__((address_space(1))) unsigned int*)g,
        (__attribute__((address_space(3))) unsigned int*)lds_base, 16, 0, 0);
#else
    *(bf16x8*)(lds_base + (size_t)lane * 8) = *(const bf16x8*)g;
#endif
}

// ================= fused cooperative kernel =================
// 512 blocks x 256 threads, 64 KiB LDS -> exactly 2 blocks/CU co-resident.
// Phase 0: W transpose fp32->bf16 Wt[t][k]   (blocks 0..47)
// Phase 1: QKV projection (each block 3 of 1536 64x64 tile-units)
// Phase 2: flash attention, no split, direct out (divide by ones-MFMA l)
__global__ __launch_bounds__(256, 2) void fused_kernel(
    const float* __restrict__ x,
    const float* __restrict__ Wq, const float* __restrict__ Wk, const float* __restrict__ Wv,
    unsigned short* __restrict__ Wt,
    unsigned short* __restrict__ qh, unsigned short* __restrict__ kh,
    unsigned short* __restrict__ vt,
    float* __restrict__ out)
{
    __shared__ __align__(16) unsigned char smem[65536];

    const int tid  = threadIdx.x;
    const int wave = tid >> 6;
    const int lane = tid & 63;
    const int quad = lane >> 4;
    const int l16  = lane & 15;

    // fragment-order staging maps (verified R5-R8)
    const int sl   = lane ^ (lane >> 3);      // producer: lane -> slot
    const int sl16 = sl >> 2, squad = sl & 3;
    const int s_   = (l16 << 2) | quad;       // consumer slot for (l16, quad)
    const int jj   = (s_ & 56) | ((s_ ^ (s_ >> 3)) & 7);

    // ---------------- phase 0: W transpose (48 blocks) ----------------
    if (blockIdx.x < 48) {
        float (*ws)[65] = (float (*)[65])smem;    // 16.6 KiB of the 64 KiB
        int wsel = blockIdx.x >> 4;
        int tile = blockIdx.x & 15;
        int tr = (tile >> 2) * 64;
        int tc = (tile & 3) * 64;
        const float* __restrict__ W = (wsel == 0) ? Wq : (wsel == 1) ? Wk : Wv;
        #pragma unroll
        for (int i = 0; i < 16; i++) {
            int row = i * 4 + (tid >> 6), col = tid & 63;
            ws[row][col] = W[(size_t)(tr + row) * DIN + tc + col];
        }
        __syncthreads();
        unsigned short* dst = Wt + (size_t)wsel * DIN * DIN;
        #pragma unroll
        for (int i = 0; i < 16; i++) {
            int orow = i * 4 + (tid >> 6), ocol = tid & 63;
            dst[(size_t)(tc + orow) * DIN + tr + ocol] = f2bf(ws[ocol][orow]);
        }
    }

    cg::this_grid().sync();

    // ---------------- phase 1: projection, 3 tile-units per block --------
    {
        typedef unsigned short FragGrp[4][64][8];   // one kb group, 4 KiB
        FragGrp* A = (FragGrp*)smem;                // 8 groups = 32 KiB
        FragGrp* B = (FragGrp*)(smem + 32768);      // 8 groups = 32 KiB

        for (int wsel = 0; wsel < 3; wsel++) {
            const int ux = blockIdx.x;
            int arow0, brow0;
            const unsigned short* Wbase;
            const float* Xbase;
            FragGrp *wdst, *xdst;
            if (wsel < 2) {
                int tt = ux >> 7, nt = ux & 127;
                arow0 = tt * 64; brow0 = nt * 64;
                Wbase = Wt + (size_t)wsel * DIN * DIN + (size_t)arow0 * DIN;
                Xbase = x + (size_t)brow0 * DIN;
                wdst = A; xdst = B;
            } else {
                int nt = ux >> 2, tt = ux & 3;
                arow0 = nt * 64; brow0 = tt * 64;
                Xbase = x + (size_t)arow0 * DIN;
                Wbase = Wt + (size_t)2 * DIN * DIN + (size_t)brow0 * DIN;
                wdst = B; xdst = A;
            }

            if (wsel) __syncthreads();   // previous unit's LDS reads done

            // stage W side via lds-dma: 8 groups per wave
            #pragma unroll
            for (int i = 0; i < 8; i++) {
                int id = wave * 8 + i;
                int kb = id >> 2, rt = id & 3;
                stage16(Wbase + (size_t)(rt * 16 + sl16) * DIN + kb * 32 + squad * 8,
                        &wdst[kb][rt][0][0], lane);
            }
            // stage x side: fp32 loads -> bf16 pack -> b128 LDS write
            #pragma unroll
            for (int i = 0; i < 8; i++) {
                int id = wave * 8 + i;
                int kb = id >> 2, rt = id & 3;
                const float4* src = (const float4*)(Xbase + (size_t)(rt * 16 + sl16) * DIN
                                                    + kb * 32 + squad * 8);
                float4 a = src[0], b = src[1];
                uint4 p = { pack_bf2(a.x, a.y), pack_bf2(a.z, a.w),
                            pack_bf2(b.x, b.y), pack_bf2(b.z, b.w) };
                *(uint4*)(&xdst[kb][rt][0][0] + (size_t)lane * 8) = p;
            }
            __syncthreads();

            f32x4 acc[4];
            #pragma unroll
            for (int c = 0; c < 4; c++) acc[c] = (f32x4){0.f, 0.f, 0.f, 0.f};
            #pragma unroll
            for (int kb = 0; kb < 8; kb++) {
                bf16x8 af = *(const bf16x8*)&A[kb][wave][jj][0];
                #pragma unroll
                for (int c = 0; c < 4; c++) {
                    bf16x8 bfr = *(const bf16x8*)&B[kb][c][jj][0];
                    acc[c] = __builtin_amdgcn_mfma_f32_16x16x32_bf16(af, bfr, acc[c], 0, 0, 0);
                }
            }

            if (wsel < 2) {
                const float scl = (wsel == 0) ? SC2 : 1.0f;
                unsigned short* __restrict__ dst0 = (wsel == 0) ? qh : kh;
                const int t0 = arow0 + wave * 16;
                const int h = t0 >> 5, d0 = (t0 & 31) + quad * 4;
                #pragma unroll
                for (int c = 0; c < 4; c++) {
                    int n = brow0 + c * 16 + l16;
                    int b = n >> 12, n12 = n & 4095;
                    unsigned int u01 = pack_bf2(acc[c][0] * scl, acc[c][1] * scl);
                    unsigned int u23 = pack_bf2(acc[c][2] * scl, acc[c][3] * scl);
                    *(uint2*)&dst0[((size_t)(b * NH + h) * SEQ + n12) * DH + d0] = make_uint2(u01, u23);
                }
            } else {
                const int n0w = arow0 + wave * 16;
                const int b = n0w >> 12, nbase = (n0w & 4095) + quad * 4;
                #pragma unroll
                for (int c = 0; c < 4; c++) {
                    int t = brow0 + c * 16;
                    int h = t >> 5, d = (t & 31) + l16;
                    unsigned int u01 = pack_bf2(acc[c][0], acc[c][1]);
                    unsigned int u23 = pack_bf2(acc[c][2], acc[c][3]);
                    *(uint2*)&vt[((size_t)(b * NH + h) * DH + d) * SEQ + nbase] = make_uint2(u01, u23);
                }
            }
        }
    }

    cg::this_grid().sync();

    // ---------------- phase 2: flash attention, direct out ----------------
    {
        unsigned short (*pbuf)[2][16][64] = (unsigned short (*)[2][16][64])smem;          // 16 KiB
        unsigned short (*kbuf)[4][64][8]  = (unsigned short (*)[4][64][8])(smem + 16384); // 8 KiB
        unsigned short (*vbuf)[4][64][8]  = (unsigned short (*)[4][64][8])(smem + 24576); // 8 KiB

        const int sw = l16 & 7;           // pbuf XOR swizzle key
        const int bh = blockIdx.x & 15;   // head -> XCD pinning
        const int qb = blockIdx.x >> 4;   // 0..31
        const int q0 = qb * 128 + wave * 32;

        const unsigned short* __restrict__ Qp = qh + (size_t)bh * SEQ * DH;
        const unsigned short* __restrict__ Kp = kh + (size_t)bh * SEQ * DH;
        const unsigned short* __restrict__ Vp = vt + (size_t)bh * DH * SEQ;

        const unsigned short* ksrc = Kp + (size_t)(wave * 16 + sl16) * DH + squad * 8;
        const int vdh = wave >> 1, vkh = wave & 1;
        const unsigned short* vsrc = Vp + (size_t)(vdh * 16 + sl16) * SEQ + vkh * 32 + squad * 8;

        bf16x8 qf[2];
        qf[0] = *(const bf16x8*)(Qp + (size_t)(q0 +      l16) * DH + quad * 8);
        qf[1] = *(const bf16x8*)(Qp + (size_t)(q0 + 16 + l16) * DH + quad * 8);

        const bf16x8 ones = {0x3F80, 0x3F80, 0x3F80, 0x3F80,
                             0x3F80, 0x3F80, 0x3F80, 0x3F80};

        f32x4 o[2][2];
        f32x4 lones[2];
        #pragma unroll
        for (int i = 0; i < 2; i++) {
            o[i][0] = (f32x4){0.f, 0.f, 0.f, 0.f};
            o[i][1] = (f32x4){0.f, 0.f, 0.f, 0.f};
            lones[i] = (f32x4){0.f, 0.f, 0.f, 0.f};
        }
        const f32x4 z = {0.f, 0.f, 0.f, 0.f};

        __syncthreads();                  // smem handoff from phase 1
        stage16(ksrc, &kbuf[0][wave][0][0], lane);
        stage16(vsrc, &vbuf[0][wave][0][0], lane);
        ksrc += 64 * DH;
        vsrc += 64;

        for (int t = 0; t < TILES; t++) {
            const int buf = t & 1;

            __syncthreads();              // tile t staged; buf^1 free

            if (t + 1 < TILES) {
                stage16(ksrc, &kbuf[buf ^ 1][wave][0][0], lane);
                stage16(vsrc, &vbuf[buf ^ 1][wave][0][0], lane);
                ksrc += 64 * DH;
                vsrc += 64;
            }

            bf16x8 kf[4], vf[4];
            #pragma unroll
            for (int c = 0; c < 4; c++) kf[c] = *(const bf16x8*)&kbuf[buf][c][jj][0];
            #pragma unroll
            for (int f = 0; f < 4; f++) vf[f] = *(const bf16x8*)&vbuf[buf][f][jj][0];

            #pragma unroll
            for (int qt = 0; qt < 2; qt++) {
                #pragma unroll
                for (int c = 0; c < 4; c++) {
                    f32x4 s = __builtin_amdgcn_mfma_f32_16x16x32_bf16(kf[c], qf[qt], z, 0, 0, 0);
                    float e0 = EXP2(s[0]);
                    float e1 = EXP2(s[1]);
                    float e2 = EXP2(s[2]);
                    float e3 = EXP2(s[3]);
                    int chs = ((c * 2 + (quad >> 1)) ^ sw) * 8 + (quad & 1) * 4;
                    *(uint2*)&pbuf[wave][qt][l16][chs] =
                        make_uint2(pack_bf2_t(e0, e1), pack_bf2_t(e2, e3));
                }
                bf16x8 pf0 = *(const bf16x8*)&pbuf[wave][qt][l16][((0 + quad) ^ sw) * 8];
                bf16x8 pf1 = *(const bf16x8*)&pbuf[wave][qt][l16][((4 + quad) ^ sw) * 8];
                o[qt][0] = __builtin_amdgcn_mfma_f32_16x16x32_bf16(pf0, vf[0], o[qt][0], 0, 0, 0);
                o[qt][0] = __builtin_amdgcn_mfma_f32_16x16x32_bf16(pf1, vf[1], o[qt][0], 0, 0, 0);
                o[qt][1] = __builtin_amdgcn_mfma_f32_16x16x32_bf16(pf0, vf[2], o[qt][1], 0, 0, 0);
                o[qt][1] = __builtin_amdgcn_mfma_f32_16x16x32_bf16(pf1, vf[3], o[qt][1], 0, 0, 0);
                lones[qt] = __builtin_amdgcn_mfma_f32_16x16x32_bf16(pf0, ones, lones[qt], 0, 0, 0);
                lones[qt] = __builtin_amdgcn_mfma_f32_16x16x32_bf16(pf1, ones, lones[qt], 0, 0, 0);
            }
        }

        // epilogue: divide by l (all 16 lanes of a row hold the same lones
        // value in C-layout), write fp32 out [b][n][h*32+d]
        const int b = bh >> 3, h = bh & 7;
        #pragma unroll
        for (int qt = 0; qt < 2; qt++) {
            #pragma unroll
            for (int r = 0; r < 4; r++) {
                float inv = 1.f / lones[qt][r];
                int n = q0 + qt * 16 + quad * 4 + r;
                float* dst = out + ((size_t)b * SEQ + n) * (NH * DH) + h * DH;
                dst[l16]      = o[qt][0][r] * inv;
                dst[16 + l16] = o[qt][1][r] * inv;
            }
        }
    }
}

extern "C" void kernel_launch(void* const* d_in, const int* in_sizes, int n_in,
                              void* d_out, int out_size, void* d_ws, size_t ws_size,
                              hipStream_t stream)
{
    const float* x  = (const float*)d_in[0];
    const float* Wq = (const float*)d_in[1];
    const float* Wk = (const float*)d_in[2];
    const float* Wv = (const float*)d_in[3];
    float* out = (float*)d_out;

    // ws: qh | kh | vt (4 MiB each) | Wt (384 KiB)
    unsigned short* qh = (unsigned short*)d_ws;
    unsigned short* kh = qh + (size_t)BH * SEQ * DH;
    unsigned short* vt = kh + (size_t)BH * SEQ * DH;
    unsigned short* Wt = vt + (size_t)BH * SEQ * DH;

    void* args[] = { (void*)&x, (void*)&Wq, (void*)&Wk, (void*)&Wv,
                     (void*)&Wt, (void*)&qh, (void*)&kh, (void*)&vt, (void*)&out };
    hipLaunchCooperativeKernel((const void*)fused_kernel, dim3(512), dim3(256),
                               args, 0, stream);
}

// Round 10
// 149.239 us; speedup vs baseline: 1.7816x; 1.7816x over previous
//
#include <hip/hip_runtime.h>
#include <math.h>

#define BATCH 2
#define SEQ   4096
#define DIN   256
#define NH    8
#define DH    32            // head dim (dk = dv = 32)
#define BH    (BATCH*NH)    // 16
#define QTILE 64            // q rows per block (shared by all 4 waves)
#define KPW   (SEQ/4)       // 1024 keys per wave (in-block key split)
#define ITERS (KPW/32)      // 32 iters of 32 keys per wave

typedef short bf16x8 __attribute__((ext_vector_type(8)));
typedef float f32x4  __attribute__((ext_vector_type(4)));

// raw v_exp_f32 (base-2). Scores bounded -> no denorm fixup needed.
#if defined(__has_builtin)
#if __has_builtin(__builtin_amdgcn_exp2f)
#define EXP2(x) __builtin_amdgcn_exp2f(x)
#else
#define EXP2_ASM 1
#endif
#else
#define EXP2_ASM 1
#endif
#ifdef EXP2_ASM
__device__ __forceinline__ float exp2_raw(float x) {
    float r;
    asm("v_exp_f32 %0, %1\n\ts_nop 1" : "=v"(r) : "v"(x));
    return r;
}
#define EXP2(x) exp2_raw(x)
#endif

#define SC2 0.25508218f     // log2(e)/sqrt(32) — folded into Q at projection

__device__ __forceinline__ unsigned short f2bf(float f) {
    unsigned int u = __builtin_bit_cast(unsigned int, f);
    u += 0x7fffu + ((u >> 16) & 1u);
    return (unsigned short)(u >> 16);
}

// pack 2 rounded bf16 (round-half-up), one v_perm + 2 adds
__device__ __forceinline__ unsigned int pack_bf2(float f0, float f1) {
    unsigned int u0 = __builtin_bit_cast(unsigned int, f0) + 0x8000u;
    unsigned int u1 = __builtin_bit_cast(unsigned int, f1) + 0x8000u;
    return __builtin_amdgcn_perm(u1, u0, 0x07060302u);
}

// pack 2 TRUNCATED bf16, single v_perm (hot attn loop). Truncation bias
// cancels exactly in softmax: l is computed from the same truncated P.
__device__ __forceinline__ unsigned int pack_bf2_t(float f0, float f1) {
    return __builtin_amdgcn_perm(__builtin_bit_cast(unsigned int, f1),
                                 __builtin_bit_cast(unsigned int, f0),
                                 0x07060302u);
}

#if defined(__has_builtin)
#if __has_builtin(__builtin_amdgcn_global_load_lds)
#define HAS_ASYNC_LDS 1
#endif
#endif

// async global->LDS, 16B/lane: wave-uniform LDS base, HW scatters lane i to
// base + i*16 (verified R5-R9).
__device__ __forceinline__ void stage16(const unsigned short* g,
                                        unsigned short* lds_base, int lane) {
#ifdef HAS_ASYNC_LDS
    __builtin_amdgcn_global_load_lds(
        (const __attribute__((address_space(1))) unsigned int*)g,
        (__attribute__((address_space(3))) unsigned int*)lds_base, 16, 0, 0);
#else
    *(bf16x8*)(lds_base + (size_t)lane * 8) = *(const bf16x8*)g;
#endif
}

// ---------------- prep: W -> Wt[t][k] bf16 (48 blocks) ----------------
__global__ __launch_bounds__(256) void prep_kernel(
    const float* __restrict__ Wq, const float* __restrict__ Wk, const float* __restrict__ Wv,
    unsigned short* __restrict__ Wt)
{
    __shared__ float ws[64][65];
    const int t = threadIdx.x;
    int wsel = blockIdx.x >> 4;
    int tile = blockIdx.x & 15;
    int tr = (tile >> 2) * 64;
    int tc = (tile & 3) * 64;
    const float* __restrict__ W = (wsel == 0) ? Wq : (wsel == 1) ? Wk : Wv;
    #pragma unroll
    for (int i = 0; i < 16; i++) {
        int row = i * 4 + (t >> 6), col = t & 63;
        ws[row][col] = W[(size_t)(tr + row) * DIN + tc + col];
    }
    __syncthreads();
    unsigned short* dst = Wt + (size_t)wsel * DIN * DIN;
    #pragma unroll
    for (int i = 0; i < 16; i++) {
        int orow = i * 4 + (t >> 6), ocol = t & 63;
        dst[(size_t)(tc + orow) * DIN + tr + ocol] = f2bf(ws[ocol][orow]);
    }
}

// ---------------- proj (R8-proven): x staged fp32->bf16 in-kernel ----------
__global__ __launch_bounds__(256) void proj_kernel(
    const float* __restrict__ x, const unsigned short* __restrict__ Wt,
    unsigned short* __restrict__ qh, unsigned short* __restrict__ kh,
    unsigned short* __restrict__ vt)
{
    __shared__ __align__(16) unsigned short abuf[8][4][64][8];  // 32 KiB
    __shared__ __align__(16) unsigned short bbuf[8][4][64][8];  // 32 KiB

    const int wsel = blockIdx.y;
    const int w    = threadIdx.x >> 6;
    const int lane = threadIdx.x & 63;
    const int quad = lane >> 4;
    const int l16  = lane & 15;

    const int sl   = lane ^ (lane >> 3);      // producer: lane -> slot
    const int sl16 = sl >> 2, squad = sl & 3;
    const int s_ = (l16 << 2) | quad;         // consumer slot for (l16, quad)
    const int jj = (s_ & 56) | ((s_ ^ (s_ >> 3)) & 7);

    int arow0, brow0;
    const unsigned short* Wbase;
    const float* Xbase;
    unsigned short (*wdst)[4][64][8];
    unsigned short (*xdst)[4][64][8];
    if (wsel < 2) {
        int tt = blockIdx.x >> 7, nt = blockIdx.x & 127;
        arow0 = tt * 64; brow0 = nt * 64;
        Wbase = Wt + (size_t)wsel * DIN * DIN + (size_t)arow0 * DIN;
        Xbase = x + (size_t)brow0 * DIN;
        wdst = abuf; xdst = bbuf;
    } else {
        int nt = blockIdx.x >> 2, tt = blockIdx.x & 3;
        arow0 = nt * 64; brow0 = tt * 64;
        Xbase = x + (size_t)arow0 * DIN;
        Wbase = Wt + (size_t)2 * DIN * DIN + (size_t)brow0 * DIN;
        wdst = bbuf; xdst = abuf;
    }

    #pragma unroll
    for (int i = 0; i < 8; i++) {
        int id = w * 8 + i;
        int kb = id >> 2, rt = id & 3;
        stage16(Wbase + (size_t)(rt * 16 + sl16) * DIN + kb * 32 + squad * 8,
                &wdst[kb][rt][0][0], lane);
    }
    #pragma unroll
    for (int i = 0; i < 8; i++) {
        int id = w * 8 + i;
        int kb = id >> 2, rt = id & 3;
        const float4* src = (const float4*)(Xbase + (size_t)(rt * 16 + sl16) * DIN
                                            + kb * 32 + squad * 8);
        float4 a = src[0], b = src[1];
        uint4 p = { pack_bf2(a.x, a.y), pack_bf2(a.z, a.w),
                    pack_bf2(b.x, b.y), pack_bf2(b.z, b.w) };
        *(uint4*)(&xdst[kb][rt][0][0] + (size_t)lane * 8) = p;
    }
    __syncthreads();

    f32x4 acc[4];
    #pragma unroll
    for (int c = 0; c < 4; c++) acc[c] = (f32x4){0.f, 0.f, 0.f, 0.f};
    #pragma unroll
    for (int kb = 0; kb < 8; kb++) {
        bf16x8 af = *(const bf16x8*)&abuf[kb][w][jj][0];
        #pragma unroll
        for (int c = 0; c < 4; c++) {
            bf16x8 bfr = *(const bf16x8*)&bbuf[kb][c][jj][0];
            acc[c] = __builtin_amdgcn_mfma_f32_16x16x32_bf16(af, bfr, acc[c], 0, 0, 0);
        }
    }

    if (wsel < 2) {
        const float scl = (wsel == 0) ? SC2 : 1.0f;
        unsigned short* __restrict__ dst0 = (wsel == 0) ? qh : kh;
        const int t0 = arow0 + w * 16;
        const int h = t0 >> 5, d0 = (t0 & 31) + quad * 4;
        #pragma unroll
        for (int c = 0; c < 4; c++) {
            int n = brow0 + c * 16 + l16;
            int b = n >> 12, n12 = n & 4095;
            unsigned int u01 = pack_bf2(acc[c][0] * scl, acc[c][1] * scl);
            unsigned int u23 = pack_bf2(acc[c][2] * scl, acc[c][3] * scl);
            *(uint2*)&dst0[((size_t)(b * NH + h) * SEQ + n12) * DH + d0] = make_uint2(u01, u23);
        }
    } else {
        const int n0w = arow0 + w * 16;
        const int b = n0w >> 12, nbase = (n0w & 4095) + quad * 4;
        #pragma unroll
        for (int c = 0; c < 4; c++) {
            int t = brow0 + c * 16;
            int h = t >> 5, d = (t & 31) + l16;
            unsigned int u01 = pack_bf2(acc[c][0], acc[c][1]);
            unsigned int u23 = pack_bf2(acc[c][2], acc[c][3]);
            *(uint2*)&vt[((size_t)(b * NH + h) * DH + d) * SEQ + nbase] = make_uint2(u01, u23);
        }
    }
}

// ---------------- Flash attention v10: wave-private staging, NO K-loop barrier
// Block = 64 q rows x full 4096 keys. Wave w owns keys [w*1024, (w+1)*1024):
// stages ITS OWN K/V 32-key tiles into ITS OWN LDS slice via lds-dma; sync is
// a wave-local s_waitcnt vmcnt(0) — zero cross-wave coupling in the loop.
// Per iter: wait vmcnt(0) -> ds_read tile t -> issue 4 DMAs for t+1 -> compute.
// One DMA batch in flight => vmcnt(0) exposes ~nothing; 4 blocks/CU hide rest.
// Epilogue: 2 barriers, cross-wave O/l reduction in reused LDS, direct out.
__global__ __launch_bounds__(256) void attn_kernel(
    const unsigned short* __restrict__ qh,
    const unsigned short* __restrict__ kh,
    const unsigned short* __restrict__ vt,
    float* __restrict__ out)
{
    // carve: kbuf 16K | vbuf 16K | pbuf 5K = 37888 B -> 4 blocks/CU
    __shared__ __align__(16) unsigned char smem[37888];
    unsigned short (*kbuf)[2][2][64][8] = (unsigned short (*)[2][2][64][8])smem;            // [wave][buf][c]
    unsigned short (*vbuf)[2][2][64][8] = (unsigned short (*)[2][2][64][8])(smem + 16384);  // [wave][buf][dh]
    unsigned short (*pbuf)[16][40]      = (unsigned short (*)[16][40])(smem + 32768);       // [wave][q16][40]

    const int tid  = threadIdx.x;
    const int wave = tid >> 6;
    const int lane = tid & 63;
    const int quad = lane >> 4;
    const int l16  = lane & 15;

    const int sl   = lane ^ (lane >> 3);      // producer: lane -> fragment slot
    const int sl16 = sl >> 2, squad = sl & 3;
    const int s_   = (l16 << 2) | quad;       // consumer slot
    const int jj   = (s_ & 56) | ((s_ ^ (s_ >> 3)) & 7);

    const int bh = blockIdx.x & 15;           // head -> XCD pinning
    const int qb = blockIdx.x >> 4;           // 0..63
    const int q0 = qb * QTILE;
    const int kstart = wave * KPW;

    const unsigned short* __restrict__ Qp = qh + (size_t)bh * SEQ * DH;
    const unsigned short* __restrict__ Kp = kh + (size_t)bh * SEQ * DH;
    const unsigned short* __restrict__ Vp = vt + (size_t)bh * DH * SEQ;

    // Q fragments (B-operand), 4 q-subtiles of 16, pre-scaled by SC2
    bf16x8 qf[4];
    #pragma unroll
    for (int i = 0; i < 4; i++)
        qf[i] = *(const bf16x8*)(Qp + (size_t)(q0 + i * 16 + l16) * DH + quad * 8);

    const bf16x8 ones = {0x3F80, 0x3F80, 0x3F80, 0x3F80,
                         0x3F80, 0x3F80, 0x3F80, 0x3F80};

    f32x4 o[4][2];
    f32x4 lones[4];
    #pragma unroll
    for (int i = 0; i < 4; i++) {
        o[i][0] = (f32x4){0.f, 0.f, 0.f, 0.f};
        o[i][1] = (f32x4){0.f, 0.f, 0.f, 0.f};
        lones[i] = (f32x4){0.f, 0.f, 0.f, 0.f};
    }
    const f32x4 z = {0.f, 0.f, 0.f, 0.f};

    // staging sources (advance per iter): K tile = 32 keys x 32 dh (2 dmas),
    // V tile = 32 d x 32 keys (2 dmas)
    const unsigned short* ksrc0 = Kp + (size_t)(kstart +      sl16) * DH + squad * 8;
    const unsigned short* ksrc1 = Kp + (size_t)(kstart + 16 + sl16) * DH + squad * 8;
    const unsigned short* vsrc0 = Vp + (size_t)(     sl16) * SEQ + kstart + squad * 8;
    const unsigned short* vsrc1 = Vp + (size_t)(16 + sl16) * SEQ + kstart + squad * 8;

    // prologue: stage tile 0 into buf 0
    stage16(ksrc0, &kbuf[wave][0][0][0][0], lane);
    stage16(ksrc1, &kbuf[wave][0][1][0][0], lane);
    stage16(vsrc0, &vbuf[wave][0][0][0][0], lane);
    stage16(vsrc1, &vbuf[wave][0][1][0][0], lane);
    ksrc0 += 32 * DH; ksrc1 += 32 * DH;
    vsrc0 += 32;      vsrc1 += 32;

    for (int t = 0; t < ITERS; t++) {
        const int buf = t & 1;

        __builtin_amdgcn_s_waitcnt(0x3F70);   // vmcnt(0): tile t's DMAs landed

        bf16x8 kf0 = *(const bf16x8*)&kbuf[wave][buf][0][jj][0];
        bf16x8 kf1 = *(const bf16x8*)&kbuf[wave][buf][1][jj][0];
        bf16x8 vf0 = *(const bf16x8*)&vbuf[wave][buf][0][jj][0];
        bf16x8 vf1 = *(const bf16x8*)&vbuf[wave][buf][1][jj][0];

        if (t + 1 < ITERS) {                  // stage t+1 into other buf
            stage16(ksrc0, &kbuf[wave][buf ^ 1][0][0][0], lane);
            stage16(ksrc1, &kbuf[wave][buf ^ 1][1][0][0], lane);
            stage16(vsrc0, &vbuf[wave][buf ^ 1][0][0][0], lane);
            stage16(vsrc1, &vbuf[wave][buf ^ 1][1][0][0], lane);
            ksrc0 += 32 * DH; ksrc1 += 32 * DH;
            vsrc0 += 32;      vsrc1 += 32;
        }

        #pragma unroll
        for (int qt = 0; qt < 4; qt++) {
            // S^T = K(32k) x Q^T(16q): rows = keys, cols = q
            f32x4 s0 = __builtin_amdgcn_mfma_f32_16x16x32_bf16(kf0, qf[qt], z, 0, 0, 0);
            f32x4 s1 = __builtin_amdgcn_mfma_f32_16x16x32_bf16(kf1, qf[qt], z, 0, 0, 0);
            #pragma unroll
            for (int c = 0; c < 2; c++) {
                const f32x4& s = c ? s1 : s0;
                float e0 = EXP2(s[0]);
                float e1 = EXP2(s[1]);
                float e2 = EXP2(s[2]);
                float e3 = EXP2(s[3]);
                // P[q=l16][keys c*16+quad*4 .. +3]: one b64 write, 2-way banks
                *(uint2*)&pbuf[wave][l16][c * 16 + quad * 4] =
                    make_uint2(pack_bf2_t(e0, e1), pack_bf2_t(e2, e3));
            }
            // P A-fragment: full 32-key contraction in one b128 read
            bf16x8 pf = *(const bf16x8*)&pbuf[wave][l16][quad * 8];
            o[qt][0] = __builtin_amdgcn_mfma_f32_16x16x32_bf16(pf, vf0, o[qt][0], 0, 0, 0);
            o[qt][1] = __builtin_amdgcn_mfma_f32_16x16x32_bf16(pf, vf1, o[qt][1], 0, 0, 0);
            lones[qt] = __builtin_amdgcn_mfma_f32_16x16x32_bf16(pf, ones, lones[qt], 0, 0, 0);
        }
    }

    // ---------------- epilogue: cross-wave reduction ----------------
    __syncthreads();   // all waves done with kbuf/vbuf -> reuse as ored
    unsigned short (*ored)[QTILE][40] = (unsigned short (*)[QTILE][40])smem;     // 20.5 KiB
    float (*lred)[QTILE] = (float (*)[QTILE])(smem + 32768);                     // 1 KiB

    #pragma unroll
    for (int qt = 0; qt < 4; qt++) {
        #pragma unroll
        for (int r = 0; r < 4; r++) {
            int q = qt * 16 + quad * 4 + r;
            ored[wave][q][l16]      = f2bf(o[qt][0][r]);
            ored[wave][q][16 + l16] = f2bf(o[qt][1][r]);
            if (l16 == 0) lred[wave][q] = lones[qt][r];
        }
    }
    __syncthreads();

    const int b = bh >> 3, h = bh & 7;
    const int q  = tid >> 2;            // 0..63
    const int d0 = (tid & 3) * 8;       // 0,8,16,24
    float acc[8];
    #pragma unroll
    for (int j = 0; j < 8; j++) acc[j] = 0.f;
    #pragma unroll
    for (int w = 0; w < 4; w++) {
        uint4 v = *(const uint4*)&ored[w][q][d0];
        acc[0] += __builtin_bit_cast(float, v.x << 16);
        acc[1] += __builtin_bit_cast(float, v.x & 0xFFFF0000u);
        acc[2] += __builtin_bit_cast(float, v.y << 16);
        acc[3] += __builtin_bit_cast(float, v.y & 0xFFFF0000u);
        acc[4] += __builtin_bit_cast(float, v.z << 16);
        acc[5] += __builtin_bit_cast(float, v.z & 0xFFFF0000u);
        acc[6] += __builtin_bit_cast(float, v.w << 16);
        acc[7] += __builtin_bit_cast(float, v.w & 0xFFFF0000u);
    }
    float ls = (lred[0][q] + lred[1][q]) + (lred[2][q] + lred[3][q]);
    float inv = 1.f / ls;
    float* dst = out + ((size_t)b * SEQ + q0 + q) * (NH * DH) + h * DH + d0;
    float4 o0 = {acc[0] * inv, acc[1] * inv, acc[2] * inv, acc[3] * inv};
    float4 o1 = {acc[4] * inv, acc[5] * inv, acc[6] * inv, acc[7] * inv};
    ((float4*)dst)[0] = o0;
    ((float4*)dst)[1] = o1;
}

extern "C" void kernel_launch(void* const* d_in, const int* in_sizes, int n_in,
                              void* d_out, int out_size, void* d_ws, size_t ws_size,
                              hipStream_t stream)
{
    const float* x  = (const float*)d_in[0];
    const float* Wq = (const float*)d_in[1];
    const float* Wk = (const float*)d_in[2];
    const float* Wv = (const float*)d_in[3];
    float* out = (float*)d_out;

    // ws: qh | kh | vt (4 MiB each) | Wt (384 KiB)
    unsigned short* qh = (unsigned short*)d_ws;
    unsigned short* kh = qh + (size_t)BH * SEQ * DH;
    unsigned short* vt = kh + (size_t)BH * SEQ * DH;
    unsigned short* Wt = vt + (size_t)BH * SEQ * DH;

    prep_kernel<<<dim3(48), 256, 0, stream>>>(Wq, Wk, Wv, Wt);
    proj_kernel<<<dim3(512, 3), 256, 0, stream>>>(x, Wt, qh, kh, vt);
    attn_kernel<<<dim3(BH * (SEQ / QTILE)), 256, 0, stream>>>(qh, kh, vt, out);
}

// Round 11
// 133.039 us; speedup vs baseline: 1.9985x; 1.1218x over previous
//
#include <hip/hip_runtime.h>
#include <math.h>

#define BATCH 2
#define SEQ   4096
#define DIN   256
#define NH    8
#define DH    32            // head dim (dk = dv = 32)
#define BH    (BATCH*NH)    // 16
#define NSPLIT 4            // key-split factor
#define KRANGE (SEQ/NSPLIT) // 1024 keys per block
#define TILES  (KRANGE/64)  // 16 tiles of 64 keys
#define QTILE  256          // q rows per block; 64 per wave (4 subtiles of 16)

typedef short bf16x8 __attribute__((ext_vector_type(8)));
typedef float f32x4  __attribute__((ext_vector_type(4)));

// raw v_exp_f32 (base-2). Scores bounded -> no denorm fixup needed.
#if defined(__has_builtin)
#if __has_builtin(__builtin_amdgcn_exp2f)
#define EXP2(x) __builtin_amdgcn_exp2f(x)
#else
#define EXP2_ASM 1
#endif
#else
#define EXP2_ASM 1
#endif
#ifdef EXP2_ASM
__device__ __forceinline__ float exp2_raw(float x) {
    float r;
    asm("v_exp_f32 %0, %1\n\ts_nop 1" : "=v"(r) : "v"(x));
    return r;
}
#define EXP2(x) exp2_raw(x)
#endif

#define SC2 0.25508218f     // log2(e)/sqrt(32) — folded into Q at projection

__device__ __forceinline__ unsigned short f2bf(float f) {
    unsigned int u = __builtin_bit_cast(unsigned int, f);
    u += 0x7fffu + ((u >> 16) & 1u);
    return (unsigned short)(u >> 16);
}

// pack 2 rounded bf16 (round-half-up), one v_perm + 2 adds
__device__ __forceinline__ unsigned int pack_bf2(float f0, float f1) {
    unsigned int u0 = __builtin_bit_cast(unsigned int, f0) + 0x8000u;
    unsigned int u1 = __builtin_bit_cast(unsigned int, f1) + 0x8000u;
    return __builtin_amdgcn_perm(u1, u0, 0x07060302u);
}

// pack 2 TRUNCATED bf16, single v_perm (hot attn loop). Truncation bias
// cancels exactly in softmax: l is computed from the same truncated P.
__device__ __forceinline__ unsigned int pack_bf2_t(float f0, float f1) {
    return __builtin_amdgcn_perm(__builtin_bit_cast(unsigned int, f1),
                                 __builtin_bit_cast(unsigned int, f0),
                                 0x07060302u);
}

#if defined(__has_builtin)
#if __has_builtin(__builtin_amdgcn_global_load_lds)
#define HAS_ASYNC_LDS 1
#endif
#endif

// async global->LDS, 16B/lane: wave-uniform LDS base, HW scatters lane i to
// base + i*16 (verified R5-R10).
__device__ __forceinline__ void stage16(const unsigned short* g,
                                        unsigned short* lds_base, int lane) {
#ifdef HAS_ASYNC_LDS
    __builtin_amdgcn_global_load_lds(
        (const __attribute__((address_space(1))) unsigned int*)g,
        (__attribute__((address_space(3))) unsigned int*)lds_base, 16, 0, 0);
#else
    *(bf16x8*)(lds_base + (size_t)lane * 8) = *(const bf16x8*)g;
#endif
}

// ---------------- prep: W -> Wt[t][k] bf16 (48 blocks) ----------------
__global__ __launch_bounds__(256) void prep_kernel(
    const float* __restrict__ Wq, const float* __restrict__ Wk, const float* __restrict__ Wv,
    unsigned short* __restrict__ Wt)
{
    __shared__ float ws[64][65];
    const int t = threadIdx.x;
    int wsel = blockIdx.x >> 4;
    int tile = blockIdx.x & 15;
    int tr = (tile >> 2) * 64;
    int tc = (tile & 3) * 64;
    const float* __restrict__ W = (wsel == 0) ? Wq : (wsel == 1) ? Wk : Wv;
    #pragma unroll
    for (int i = 0; i < 16; i++) {
        int row = i * 4 + (t >> 6), col = t & 63;
        ws[row][col] = W[(size_t)(tr + row) * DIN + tc + col];
    }
    __syncthreads();
    unsigned short* dst = Wt + (size_t)wsel * DIN * DIN;
    #pragma unroll
    for (int i = 0; i < 16; i++) {
        int orow = i * 4 + (t >> 6), ocol = t & 63;
        dst[(size_t)(tc + orow) * DIN + tr + ocol] = f2bf(ws[ocol][orow]);
    }
}

// ---------------- proj (R8-proven): x staged fp32->bf16 in-kernel ----------
__global__ __launch_bounds__(256) void proj_kernel(
    const float* __restrict__ x, const unsigned short* __restrict__ Wt,
    unsigned short* __restrict__ qh, unsigned short* __restrict__ kh,
    unsigned short* __restrict__ vt)
{
    __shared__ __align__(16) unsigned short abuf[8][4][64][8];  // 32 KiB
    __shared__ __align__(16) unsigned short bbuf[8][4][64][8];  // 32 KiB

    const int wsel = blockIdx.y;
    const int w    = threadIdx.x >> 6;
    const int lane = threadIdx.x & 63;
    const int quad = lane >> 4;
    const int l16  = lane & 15;

    const int sl   = lane ^ (lane >> 3);      // producer: lane -> slot
    const int sl16 = sl >> 2, squad = sl & 3;
    const int s_ = (l16 << 2) | quad;         // consumer slot for (l16, quad)
    const int jj = (s_ & 56) | ((s_ ^ (s_ >> 3)) & 7);

    int arow0, brow0;
    const unsigned short* Wbase;
    const float* Xbase;
    unsigned short (*wdst)[4][64][8];
    unsigned short (*xdst)[4][64][8];
    if (wsel < 2) {
        int tt = blockIdx.x >> 7, nt = blockIdx.x & 127;
        arow0 = tt * 64; brow0 = nt * 64;
        Wbase = Wt + (size_t)wsel * DIN * DIN + (size_t)arow0 * DIN;
        Xbase = x + (size_t)brow0 * DIN;
        wdst = abuf; xdst = bbuf;
    } else {
        int nt = blockIdx.x >> 2, tt = blockIdx.x & 3;
        arow0 = nt * 64; brow0 = tt * 64;
        Xbase = x + (size_t)arow0 * DIN;
        Wbase = Wt + (size_t)2 * DIN * DIN + (size_t)brow0 * DIN;
        wdst = bbuf; xdst = abuf;
    }

    #pragma unroll
    for (int i = 0; i < 8; i++) {
        int id = w * 8 + i;
        int kb = id >> 2, rt = id & 3;
        stage16(Wbase + (size_t)(rt * 16 + sl16) * DIN + kb * 32 + squad * 8,
                &wdst[kb][rt][0][0], lane);
    }
    #pragma unroll
    for (int i = 0; i < 8; i++) {
        int id = w * 8 + i;
        int kb = id >> 2, rt = id & 3;
        const float4* src = (const float4*)(Xbase + (size_t)(rt * 16 + sl16) * DIN
                                            + kb * 32 + squad * 8);
        float4 a = src[0], b = src[1];
        uint4 p = { pack_bf2(a.x, a.y), pack_bf2(a.z, a.w),
                    pack_bf2(b.x, b.y), pack_bf2(b.z, b.w) };
        *(uint4*)(&xdst[kb][rt][0][0] + (size_t)lane * 8) = p;
    }
    __syncthreads();

    f32x4 acc[4];
    #pragma unroll
    for (int c = 0; c < 4; c++) acc[c] = (f32x4){0.f, 0.f, 0.f, 0.f};
    #pragma unroll
    for (int kb = 0; kb < 8; kb++) {
        bf16x8 af = *(const bf16x8*)&abuf[kb][w][jj][0];
        #pragma unroll
        for (int c = 0; c < 4; c++) {
            bf16x8 bfr = *(const bf16x8*)&bbuf[kb][c][jj][0];
            acc[c] = __builtin_amdgcn_mfma_f32_16x16x32_bf16(af, bfr, acc[c], 0, 0, 0);
        }
    }

    if (wsel < 2) {
        const float scl = (wsel == 0) ? SC2 : 1.0f;
        unsigned short* __restrict__ dst0 = (wsel == 0) ? qh : kh;
        const int t0 = arow0 + w * 16;
        const int h = t0 >> 5, d0 = (t0 & 31) + quad * 4;
        #pragma unroll
        for (int c = 0; c < 4; c++) {
            int n = brow0 + c * 16 + l16;
            int b = n >> 12, n12 = n & 4095;
            unsigned int u01 = pack_bf2(acc[c][0] * scl, acc[c][1] * scl);
            unsigned int u23 = pack_bf2(acc[c][2] * scl, acc[c][3] * scl);
            *(uint2*)&dst0[((size_t)(b * NH + h) * SEQ + n12) * DH + d0] = make_uint2(u01, u23);
        }
    } else {
        const int n0w = arow0 + w * 16;
        const int b = n0w >> 12, nbase = (n0w & 4095) + quad * 4;
        #pragma unroll
        for (int c = 0; c < 4; c++) {
            int t = brow0 + c * 16;
            int h = t >> 5, d = (t & 31) + l16;
            unsigned int u01 = pack_bf2(acc[c][0], acc[c][1]);
            unsigned int u23 = pack_bf2(acc[c][2], acc[c][3]);
            *(uint2*)&vt[((size_t)(b * NH + h) * DH + d) * SEQ + nbase] = make_uint2(u01, u23);
        }
    }
}

// ---------------- Flash attention v11: 64 q per wave, amortized K/V LDS ----
// Block = 256 q (64/wave) x 1024 keys. R7's proven 2-barrier loop skeleton;
// shared 64-key K/V tile staged via lds-dma, each wave reads kf/vf ONCE and
// amortizes over 4 q-subtiles (halves the dominant LDS-read term vs R8).
// pbuf parity regions (qt&1) let qt+1's QK/exp overlap qt's PV.
__global__ __launch_bounds__(256, 4) void attn_kernel(
    const unsigned short* __restrict__ qh,
    const unsigned short* __restrict__ kh,
    const unsigned short* __restrict__ vt,
    unsigned short* __restrict__ po, float* __restrict__ pl)
{
    __shared__ __align__(16) unsigned short pbuf[4][2][16][64];  // 16 KiB
    __shared__ __align__(16) unsigned short kbuf[2][4][64][8];   // 8 KiB
    __shared__ __align__(16) unsigned short vbuf[2][4][64][8];   // 8 KiB

    const int tid  = threadIdx.x;
    const int wave = tid >> 6;
    const int lane = tid & 63;
    const int quad = lane >> 4;
    const int l16  = lane & 15;
    const int sw   = l16 & 7;         // pbuf XOR swizzle key

    const int bh = blockIdx.x & 15;   // head -> XCD pinning
    const int qb = (blockIdx.x >> 4) & 15;
    const int ks = blockIdx.x >> 8;   // key-split 0..3
    const int q0 = qb * QTILE + wave * 64;
    const int kbase = ks * KRANGE;

    const unsigned short* __restrict__ Qp = qh + (size_t)bh * SEQ * DH;
    const unsigned short* __restrict__ Kp = kh + (size_t)bh * SEQ * DH;
    const unsigned short* __restrict__ Vp = vt + (size_t)bh * DH * SEQ;

    const int sl    = lane ^ (lane >> 3);
    const int sl16  = sl >> 2, squad = sl & 3;
    const unsigned short* ksrc = Kp + (size_t)(kbase + wave * 16 + sl16) * DH + squad * 8;
    const int vdh = wave >> 1, vkh = wave & 1;
    const unsigned short* vsrc = Vp + (size_t)(vdh * 16 + sl16) * SEQ + kbase + vkh * 32 + squad * 8;

    const int s_ = (l16 << 2) | quad;
    const int jj = (s_ & 56) | ((s_ ^ (s_ >> 3)) & 7);

    bf16x8 qf[4];
    #pragma unroll
    for (int i = 0; i < 4; i++)
        qf[i] = *(const bf16x8*)(Qp + (size_t)(q0 + i * 16 + l16) * DH + quad * 8);

    const bf16x8 ones = {0x3F80, 0x3F80, 0x3F80, 0x3F80,
                         0x3F80, 0x3F80, 0x3F80, 0x3F80};

    f32x4 o[4][2];
    f32x4 lones[4];
    #pragma unroll
    for (int i = 0; i < 4; i++) {
        o[i][0] = (f32x4){0.f, 0.f, 0.f, 0.f};
        o[i][1] = (f32x4){0.f, 0.f, 0.f, 0.f};
        lones[i] = (f32x4){0.f, 0.f, 0.f, 0.f};
    }
    const f32x4 z = {0.f, 0.f, 0.f, 0.f};

    stage16(ksrc, &kbuf[0][wave][0][0], lane);
    stage16(vsrc, &vbuf[0][wave][0][0], lane);
    ksrc += 64 * DH;
    vsrc += 64;

    for (int t = 0; t < TILES; t++) {
        const int buf = t & 1;

        __syncthreads();   // tile t staged; buf^1 free

        if (t + 1 < TILES) {
            stage16(ksrc, &kbuf[buf ^ 1][wave][0][0], lane);
            stage16(vsrc, &vbuf[buf ^ 1][wave][0][0], lane);
            ksrc += 64 * DH;
            vsrc += 64;
        }

        // read shared K/V fragments ONCE per wave, reuse across 4 q-subtiles
        bf16x8 kf[4], vf[4];
        #pragma unroll
        for (int c = 0; c < 4; c++) kf[c] = *(const bf16x8*)&kbuf[buf][c][jj][0];
        #pragma unroll
        for (int f = 0; f < 4; f++) vf[f] = *(const bf16x8*)&vbuf[buf][f][jj][0];

        #pragma unroll
        for (int qt = 0; qt < 4; qt++) {
            const int pr = qt & 1;    // pbuf parity region
            #pragma unroll
            for (int c = 0; c < 4; c++) {
                f32x4 s = __builtin_amdgcn_mfma_f32_16x16x32_bf16(kf[c], qf[qt], z, 0, 0, 0);
                float e0 = EXP2(s[0]);
                float e1 = EXP2(s[1]);
                float e2 = EXP2(s[2]);
                float e3 = EXP2(s[3]);
                int chs = ((c * 2 + (quad >> 1)) ^ sw) * 8 + (quad & 1) * 4;
                *(uint2*)&pbuf[wave][pr][l16][chs] =
                    make_uint2(pack_bf2_t(e0, e1), pack_bf2_t(e2, e3));
            }
            bf16x8 pf0 = *(const bf16x8*)&pbuf[wave][pr][l16][((0 + quad) ^ sw) * 8];
            bf16x8 pf1 = *(const bf16x8*)&pbuf[wave][pr][l16][((4 + quad) ^ sw) * 8];
            o[qt][0] = __builtin_amdgcn_mfma_f32_16x16x32_bf16(pf0, vf[0], o[qt][0], 0, 0, 0);
            o[qt][0] = __builtin_amdgcn_mfma_f32_16x16x32_bf16(pf1, vf[1], o[qt][0], 0, 0, 0);
            o[qt][1] = __builtin_amdgcn_mfma_f32_16x16x32_bf16(pf0, vf[2], o[qt][1], 0, 0, 0);
            o[qt][1] = __builtin_amdgcn_mfma_f32_16x16x32_bf16(pf1, vf[3], o[qt][1], 0, 0, 0);
            lones[qt] = __builtin_amdgcn_mfma_f32_16x16x32_bf16(pf0, ones, lones[qt], 0, 0, 0);
            lones[qt] = __builtin_amdgcn_mfma_f32_16x16x32_bf16(pf1, ones, lones[qt], 0, 0, 0);
        }
    }

    // epilogue: bf16 partial O + fp32 partial l (lones rows align with o rows)
    const size_t obase = (size_t)(ks * BH + bh) * SEQ;
    #pragma unroll
    for (int qt = 0; qt < 4; qt++) {
        if (l16 == 0) {
            #pragma unroll
            for (int r = 0; r < 4; r++)
                pl[obase + q0 + qt * 16 + quad * 4 + r] = lones[qt][r];
        }
        #pragma unroll
        for (int r = 0; r < 4; r++) {
            int n = q0 + qt * 16 + quad * 4 + r;
            unsigned short* dst = po + (obase + n) * DH;
            dst[l16]      = f2bf(o[qt][0][r]);
            dst[16 + l16] = f2bf(o[qt][1][r]);
        }
    }
}

// ---------------- merge: sum bf16 split partials, divide, write out ---------
__global__ __launch_bounds__(256) void merge_kernel(
    const unsigned short* __restrict__ po, const float* __restrict__ pl,
    float* __restrict__ out)
{
    int t    = blockIdx.x * 256 + threadIdx.x;   // 0 .. 512K-1
    int d8   = t & 7;
    int pair = t >> 3;
    int bh   = pair >> 12;
    int n    = pair & 4095;
    float s0 = 0.f, s1 = 0.f, s2 = 0.f, s3 = 0.f, ls = 0.f;
    #pragma unroll
    for (int sp = 0; sp < NSPLIT; sp++) {
        size_t base = (size_t)(sp * BH + bh) * SEQ + n;
        uint2 v = ((const uint2*)(po + base * DH))[d8];
        s0 += __builtin_bit_cast(float, v.x << 16);
        s1 += __builtin_bit_cast(float, v.x & 0xFFFF0000u);
        s2 += __builtin_bit_cast(float, v.y << 16);
        s3 += __builtin_bit_cast(float, v.y & 0xFFFF0000u);
        ls += pl[base];
    }
    float inv = 1.f / ls;
    int b = bh >> 3, h = bh & 7;
    float4 o = {s0 * inv, s1 * inv, s2 * inv, s3 * inv};
    ((float4*)(out + ((size_t)b * SEQ + n) * (NH * DH) + h * DH))[d8] = o;
}

extern "C" void kernel_launch(void* const* d_in, const int* in_sizes, int n_in,
                              void* d_out, int out_size, void* d_ws, size_t ws_size,
                              hipStream_t stream)
{
    const float* x  = (const float*)d_in[0];
    const float* Wq = (const float*)d_in[1];
    const float* Wk = (const float*)d_in[2];
    const float* Wv = (const float*)d_in[3];
    float* out = (float*)d_out;

    // ws: qh|kh|vt (4 MiB each) | Wt (384 KiB) | po (16 MiB bf16) | pl (1 MiB f32)
    unsigned short* qh = (unsigned short*)d_ws;
    unsigned short* kh = qh + (size_t)BH * SEQ * DH;
    unsigned short* vt = kh + (size_t)BH * SEQ * DH;
    unsigned short* Wt = vt + (size_t)BH * SEQ * DH;
    unsigned short* po = Wt + 3 * DIN * DIN;
    float* pl = (float*)(po + (size_t)NSPLIT * BH * SEQ * DH);

    prep_kernel<<<dim3(48), 256, 0, stream>>>(Wq, Wk, Wv, Wt);
    proj_kernel<<<dim3(512, 3), 256, 0, stream>>>(x, Wt, qh, kh, vt);
    attn_kernel<<<dim3(BH * (SEQ / QTILE) * NSPLIT), 256, 0, stream>>>(qh, kh, vt, po, pl);
    merge_kernel<<<dim3(2048), 256, 0, stream>>>(po, pl, out);
}